// Round 7
// baseline (250.727 us; speedup 1.0000x reference)
//
#include <hip/hip_runtime.h>
#include <hip/hip_cooperative_groups.h>
namespace cg = cooperative_groups;

#define HW    262144      // 512*512
#define BNUM  4
#define NC    33          // labels 0..32
#define NI    32          // instance channels

#define NB     2048       // t-space bins
#define BSCALE 128.0f     // NB / TMAX (TMAX = 16)
#define EG     4096       // e-grid bins in scan
#define ESCALE 2048.0f    // EG / 2.0

typedef unsigned long long ull;

// word (float/u32) offsets within each sample's workspace slice
#define W_TH   0                    // u64[NB] packed (pos<<32)|neg -> 4096 words
#define W_E0   4096
#define W_E1   (W_E0 + NC)          // 4129
#define W_SS   (W_E1 + NC)          // 4162
#define W_SS2  (W_SS + NC)          // 4195
#define W_CNT  (W_SS2 + NC)         // 4228
#define W_STRIDE 4262               // even (u64-aligned t-hist)
#define W_FIN  (BNUM * W_STRIDE)    // 4 loss slots + counter
#define NWORDS (W_FIN + 8)

union SMem {
  struct { float a0[8][NC], a1[8][NC], as1[8][NC], as2[8][NC]; unsigned ac[8][NC]; } a;
  struct { unsigned hist[NB * 4]; float4 cons[NC]; } b;                 // 32 KB + 528 B
  struct { unsigned ep[EG], en[EG]; ull wsum[8]; float red[8]; float vart; } c;  // 32 KB + 100 B
};

__global__ void __launch_bounds__(512, 4) fused_kernel(
    const float* __restrict__ emb, const float* __restrict__ sig,
    const int* __restrict__ gt, float* __restrict__ ws,
    float* __restrict__ out) {
  cg::grid_group grid = cg::this_grid();
  __shared__ SMem sm;
  int t = threadIdx.x;
  int bid = blockIdx.x;
  int s = bid >> 7;            // sample  (512 blocks = 4 samples x 128)
  int lb = bid & 127;          // block within sample
  float* wsS = ws + (size_t)s * W_STRIDE;

  // ================= Phase A: zero ws slice + per-instance stats =================
  int gid = bid * 512 + t;
  if (gid < NWORDS) ((unsigned*)ws)[gid] = 0u;
  for (int k = t; k < 8 * NC * 5; k += 512) ((float*)&sm.a)[k] = 0.f;
  __syncthreads();

  const float* e0p = emb + (size_t)s * 2 * HW;
  const float* e1p = e0p + HW;
  const float* sp  = sig + (size_t)s * HW;
  const int*   gp  = gt  + (size_t)s * HW;
  int w = t >> 6;
  int idx = lb * 2048 + t * 4;
  int4   lbl = *(const int4*)(gp + idx);
  float4 x   = *(const float4*)(e0p + idx);
  float4 y   = *(const float4*)(e1p + idx);
  float4 sg4 = *(const float4*)(sp + idx);
#define ACC(L, X, Y, SG)                                                  \
  if (L > 0) {                                                            \
    atomicAdd(&sm.a.a0[w][L], X);  atomicAdd(&sm.a.a1[w][L], Y);          \
    atomicAdd(&sm.a.as1[w][L], SG); atomicAdd(&sm.a.as2[w][L], (SG)*(SG));\
    atomicAdd(&sm.a.ac[w][L], 1u);                                        \
  }
  ACC(lbl.x, x.x, y.x, sg4.x)
  ACC(lbl.y, x.y, y.y, sg4.y)
  ACC(lbl.z, x.z, y.z, sg4.z)
  ACC(lbl.w, x.w, y.w, sg4.w)
#undef ACC
  __syncthreads();
  // cross-wave reduce into registers (held across grid.sync)
  float r0 = 0.f, r1 = 0.f, r2 = 0.f, r3 = 0.f;
  unsigned rc = 0u;
  if (t >= 1 && t < NC) {
    #pragma unroll
    for (int i = 0; i < 8; ++i) {
      r0 += sm.a.a0[i][t]; r1 += sm.a.a1[i][t];
      r2 += sm.a.as1[i][t]; r3 += sm.a.as2[i][t];
      rc += sm.a.ac[i][t];
    }
  }
  grid.sync();   // all ws zeroing complete
  if (rc) {
    atomicAdd(&wsS[W_E0 + t], r0);
    atomicAdd(&wsS[W_E1 + t], r1);
    atomicAdd(&wsS[W_SS + t], r2);
    atomicAdd(&wsS[W_SS2 + t], r3);
    atomicAdd((unsigned*)wsS + (W_CNT + t), rc);
  }
  grid.sync();   // stats complete, visible grid-wide

  // ================= Phase B: t-space histogram (FMA-form bins) =================
  for (int k = t; k < NB * 4; k += 512) sm.b.hist[k] = 0u;
  if (t >= 1 && t < NC) {
    float inv = 1.0f / (float)((const unsigned*)wsS)[W_CNT + t];
    float c0 = wsS[W_E0 + t] * inv;
    float c1 = wsS[W_E1 + t] * inv;
    float sgm = wsS[W_SS + t] * inv;
    float Q = 0.5f / (sgm * sgm) * BSCALE;
    float4 c;
    c.x = Q;
    c.y = -2.0f * Q * c0;
    c.z = -2.0f * Q * c1;
    c.w = Q * (c0 * c0 + c1 * c1);
    sm.b.cons[t] = c;
  }
  __syncthreads();
  float4 ss;
  ss.x = fmaf(x.x, x.x, y.x * y.x);
  ss.y = fmaf(x.y, x.y, y.y * y.y);
  ss.z = fmaf(x.z, x.z, y.z * y.z);
  ss.w = fmaf(x.w, x.w, y.w * y.w);
  unsigned* hr = sm.b.hist + (t & 3);
  #pragma unroll 4
  for (int n = 1; n <= NI; ++n) {
    float4 C = sm.b.cons[n];
#define ITEM(P0, P1, SV, L)                                            \
    {                                                                  \
      float bf = fmaf(C.x, SV, fmaf(C.y, P0, fmaf(C.z, P1, C.w)));     \
      int ib = (int)bf;                                                \
      bool pos = (L == n);                                             \
      if (pos) ib = min(ib, NB - 1);                                   \
      if (ib < NB) atomicAdd(&hr[ib << 2], pos ? 0x10000u : 1u);       \
    }
    ITEM(x.x, y.x, ss.x, lbl.x)
    ITEM(x.y, y.y, ss.y, lbl.y)
    ITEM(x.z, y.z, ss.z, lbl.z)
    ITEM(x.w, y.w, ss.w, lbl.w)
#undef ITEM
  }
  __syncthreads();
  {
    ull* th = (ull*)wsS;  // W_TH == 0
    for (int k = t; k < NB; k += 512) {
      unsigned v = sm.b.hist[k*4] + sm.b.hist[k*4+1] + sm.b.hist[k*4+2] + sm.b.hist[k*4+3];
      if (v) {
        ull add = ((ull)(v >> 16) << 32) | (v & 0xFFFFu);
        atomicAdd(&th[k], add);
      }
    }
  }
  grid.sync();   // t-hist complete, visible grid-wide

  // ================= Phase C: blocks 0..3 — resample + Jaccard scan =============
  if (bid >= BNUM) return;
  int sc = bid;
  float* wsC = ws + (size_t)sc * W_STRIDE;
  const ull* th = (const ull*)wsC;
  const unsigned* wsu = (const unsigned*)wsC;
  int lane = t & 63, wid = t >> 6;
  for (int k = t; k < EG; k += 512) { sm.c.ep[k] = 0u; sm.c.en[k] = 0u; }
  // pooled variance term: vart = S_total * (sum_n 1/c_n) / NI
  if (wid == 0) {
    float S = 0.f, rcp = 0.f;
    if (lane >= 1 && lane < NC) {
      float c = (float)wsu[W_CNT + lane];
      float sg = wsC[W_SS + lane] / c;
      S = wsC[W_SS2 + lane] - c * sg * sg;
      rcp = 1.0f / c;
    }
    for (int o = 32; o; o >>= 1) {
      S   += __shfl_down(S, o);
      rcp += __shfl_down(rcp, o);
    }
    if (lane == 0) sm.c.vart = S * rcp / (float)NI;
  }
  __syncthreads();
  // scatter t-bins onto e-grid
  for (int b = t; b < NB; b += 512) {
    ull v = th[b];
    unsigned pos = (unsigned)(v >> 32), neg = (unsigned)(v & 0xFFFFFFFFu);
    if (pos | neg) {
      float tc = ((float)b + 0.5f) * (1.0f / BSCALE);
      float ex = __expf(-tc);
      if (pos) {
        float e = 2.0f - 2.0f * ex;
        int k = (int)(e * ESCALE); if (k > EG - 1) k = EG - 1;
        atomicAdd(&sm.c.ep[k], pos);
      }
      if (neg) {
        float e = 2.0f * ex;
        int k = (int)(e * ESCALE); if (k > EG - 1) k = EG - 1;
        atomicAdd(&sm.c.en[k], neg);
      }
    }
  }
  __syncthreads();
  const int CH = EG / 512;  // 8
  int j0 = t * CH;
  unsigned np = 0, nn = 0;
  for (int k = 0; k < CH; ++k) {
    int b = EG - 1 - (j0 + k);
    np += sm.c.ep[b]; nn += sm.c.en[b];
  }
  ull v = ((ull)np << 32) | (ull)nn;
  ull inc = v;
  for (int o = 1; o < 64; o <<= 1) {
    ull u = __shfl_up(inc, o);
    if (lane >= o) inc += u;
  }
  if (lane == 63) sm.c.wsum[wid] = inc;
  __syncthreads();
  ull offset = 0, total = 0;
  for (int i = 0; i < 8; ++i) {
    ull xr = sm.c.wsum[i];
    if (i < wid) offset += xr;
    total += xr;
  }
  ull excl = offset + inc - v;
  float P = (float)(unsigned)(total >> 32);
  unsigned p = (unsigned)(excl >> 32), f = (unsigned)(excl & 0xFFFFFFFFu);
  float jprev = 1.0f - (P - (float)p) / (P + (float)f);
  float contrib = 0.f;
  for (int k = 0; k < CH; ++k) {
    int b = EG - 1 - (j0 + k);
    unsigned ap_ = sm.c.ep[b], an_ = sm.c.en[b];
    if (ap_ | an_) {
      p += ap_; f += an_;
      float j = 1.0f - (P - (float)p) / (P + (float)f);
      float e = ((float)b + 0.5f) * (2.0f / EG);
      contrib += e * (j - jprev);
      jprev = j;
    }
  }
  for (int o = 32; o; o >>= 1) contrib += __shfl_down(contrib, o);
  if (lane == 0) sm.c.red[wid] = contrib;
  __syncthreads();
  if (t == 0) {
    float tot = 0.f;
    for (int i = 0; i < 8; ++i) tot += sm.c.red[i];
    float loss = tot + sm.c.vart;
    float* fin = ws + W_FIN;
    unsigned* cnt = (unsigned*)(fin + 4);
    atomicExch(&fin[sc], loss);
    unsigned old = atomicAdd(cnt, 1u);
    if (old == BNUM - 1) {
      float a = 0.f;
      for (int i = 0; i < BNUM; ++i) a += atomicAdd(&fin[i], 0.0f);
      out[0] = a * (1.0f / BNUM);
    }
  }
}

extern "C" void kernel_launch(void* const* d_in, const int* in_sizes, int n_in,
                              void* d_out, int out_size, void* d_ws, size_t ws_size,
                              hipStream_t stream) {
  const float* emb = (const float*)d_in[0];   // [4,2,512,512]
  const float* sig = (const float*)d_in[1];   // [4,1,512,512]
  const int*   gt  = (const int*)d_in[2];     // [4,1,512,512]
  float* out = (float*)d_out;
  float* ws  = (float*)d_ws;

  void* args[] = {(void*)&emb, (void*)&sig, (void*)&gt, (void*)&ws, (void*)&out};
  hipLaunchCooperativeKernel((const void*)fused_kernel, dim3(512), dim3(512),
                             args, 0, stream);
}

// Round 8
// 120.588 us; speedup vs baseline: 2.0792x; 2.0792x over previous
//
#include <hip/hip_runtime.h>

#define HW    262144      // 512*512
#define BNUM  4
#define NC    33          // labels 0..32
#define NI    32          // instance channels

#define NB     2048       // t-space bins
#define BSCALE 128.0f     // NB / TMAX (TMAX = 16)
#define EG     4096       // e-grid bins in scan
#define ESCALE 2048.0f    // EG / 2.0

typedef unsigned long long ull;

// ws layout in 32-bit words:
//   [0 .. 16384)           t-hist: u64[NB] per sample, sample s at word 4096*s
//   [W_PART .. +42240)     float part[5*33][256]; element [(f*33+n)][s*64+j]
//   [W_FIN .. +16)         fin: [0..3] losses, [4] global cnt, [8+s] arrival cnt
#define W_PART 16384
#define W_FIN  (W_PART + 5 * 33 * 256)   // 58624

// ---------------- Pass A: per-instance stats -> deterministic partials.
// Also zeroes the t-hist + fin regions (replaces the memset dispatch).
__global__ void __launch_bounds__(256) stats_kernel(
    const float* __restrict__ emb, const float* __restrict__ sig,
    const int* __restrict__ gt, float* __restrict__ ws) {
  int s = blockIdx.y;          // sample
  int j = blockIdx.x;          // 0..63 block within sample
  int t = threadIdx.x;
  int w = t >> 6;
  __shared__ float acc[4][165];   // [wave][f*33+n], f: e0,e1,ss,ss2,cnt
  // zero my 64-word share of t-hist; block 0 zeroes fin
  int bid = s * 64 + j;           // 0..255
  unsigned* wsu = (unsigned*)ws;
  if (t < 64) wsu[bid * 64 + t] = 0u;
  if (bid == 0 && t < 16) wsu[W_FIN + t] = 0u;
  for (int k = t; k < 4 * 165; k += 256) ((float*)acc)[k] = 0.f;
  __syncthreads();
  const float* e0p = emb + (size_t)s * 2 * HW;
  const float* e1p = e0p + HW;
  const float* sp  = sig + (size_t)s * HW;
  const int*   gp  = gt  + (size_t)s * HW;
  #pragma unroll
  for (int i = 0; i < 4; ++i) {
    int idx = j * 4096 + i * 1024 + t * 4;
    int4   lb = *(const int4*)(gp + idx);
    float4 x  = *(const float4*)(e0p + idx);
    float4 y  = *(const float4*)(e1p + idx);
    float4 sg = *(const float4*)(sp + idx);
#define ACC(L, X, Y, SG)                                                   \
    if (L > 0) {                                                           \
      atomicAdd(&acc[w][L], X);        atomicAdd(&acc[w][33 + L], Y);      \
      atomicAdd(&acc[w][66 + L], SG);  atomicAdd(&acc[w][99 + L], (SG)*(SG)); \
      atomicAdd(&acc[w][132 + L], 1.0f);                                   \
    }
    ACC(lb.x, x.x, y.x, sg.x)
    ACC(lb.y, x.y, y.y, sg.y)
    ACC(lb.z, x.z, y.z, sg.z)
    ACC(lb.w, x.w, y.w, sg.w)
#undef ACC
  }
  __syncthreads();
  if (t < 165) {
    float v = acc[0][t] + acc[1][t] + acc[2][t] + acc[3][t];
    ws[W_PART + t * 256 + s * 64 + j] = v;   // plain store, unique slot
  }
}

// ---------------- Pass B+C fused: hist; last-arriving block per sample scans.
__global__ void __launch_bounds__(512) hist_scan_kernel(
    const float* __restrict__ emb, const int* __restrict__ gt,
    float* __restrict__ ws, float* __restrict__ out) {
  int s  = blockIdx.y;
  int lb = blockIdx.x;           // 0..127
  __shared__ unsigned hist[NB * 4];   // 32 KB; reused as ep/en in scan phase
  __shared__ float sums[165];
  __shared__ float4 cons[NC];
  __shared__ ull wsum[8];
  __shared__ float red[8];
  __shared__ float vart_s;
  __shared__ int flag;
  int t = threadIdx.x;
  int lane = t & 63, wid = t >> 6;
  for (int k = t; k < NB * 4; k += 512) hist[k] = 0u;
  // sum the 64 per-block partials for this sample (vectorized, L2 hits)
  if (t < 165) {
    const float4* pp = (const float4*)(ws + W_PART + t * 256 + s * 64);
    float sum = 0.f;
    #pragma unroll
    for (int i = 0; i < 16; ++i) { float4 v = pp[i]; sum += v.x + v.y + v.z + v.w; }
    sums[t] = sum;
  }
  __syncthreads();
  if (t >= 1 && t < NC) {
    float c = sums[132 + t];
    float4 C;
    if (c > 0.f) {
      float inv = 1.0f / c;
      float c0 = sums[t] * inv, c1 = sums[33 + t] * inv, sgm = sums[66 + t] * inv;
      float Q = 0.5f / (sgm * sgm) * BSCALE;
      C.x = Q; C.y = -2.0f * Q * c0; C.z = -2.0f * Q * c1;
      C.w = Q * (c0 * c0 + c1 * c1);
    } else {
      C.x = 0.f; C.y = 0.f; C.z = 0.f; C.w = (float)NB;  // never bins
    }
    cons[t] = C;
  }
  __syncthreads();
  const float* e0p = emb + (size_t)s * 2 * HW;
  const float* e1p = e0p + HW;
  const int*   gp  = gt  + (size_t)s * HW;
  int idx = lb * 2048 + t * 4;
  int4   lbl = *(const int4*)(gp + idx);
  float4 px  = *(const float4*)(e0p + idx);
  float4 py  = *(const float4*)(e1p + idx);
  float4 ss;
  ss.x = fmaf(px.x, px.x, py.x * py.x);
  ss.y = fmaf(px.y, px.y, py.y * py.y);
  ss.z = fmaf(px.z, px.z, py.z * py.z);
  ss.w = fmaf(px.w, px.w, py.w * py.w);
  unsigned* hr = hist + (t & 3);
  #pragma unroll 4
  for (int n = 1; n <= NI; ++n) {
    float4 C = cons[n];
#define ITEM(P0, P1, SV, L)                                            \
    {                                                                  \
      float bf = fmaf(C.x, SV, fmaf(C.y, P0, fmaf(C.z, P1, C.w)));     \
      int ib = (int)bf;                                                \
      bool pos = (L == n);                                             \
      if (pos) ib = min(ib, NB - 1);                                   \
      if (ib < NB) atomicAdd(&hr[ib << 2], pos ? 0x10000u : 1u);       \
    }
    ITEM(px.x, py.x, ss.x, lbl.x)
    ITEM(px.y, py.y, ss.y, lbl.y)
    ITEM(px.z, py.z, ss.z, lbl.z)
    ITEM(px.w, py.w, ss.w, lbl.w)
#undef ITEM
  }
  __syncthreads();
  // flush to the sample's global t-hist (device-scope atomics)
  ull* th = ((ull*)ws) + (size_t)s * NB;
  for (int k = t; k < NB; k += 512) {
    unsigned v = hist[k*4] + hist[k*4+1] + hist[k*4+2] + hist[k*4+3];
    if (v) {
      ull add = ((ull)(v >> 16) << 32) | (v & 0xFFFFu);
      atomicAdd(&th[k], add);
    }
  }
  __syncthreads();
  if (t == 0) {
    __threadfence();   // release our flush before arrival
    unsigned* cnt = (unsigned*)(ws + W_FIN);
    flag = (atomicAdd(&cnt[8 + s], 1u) == 127u);
  }
  __syncthreads();
  if (!flag) return;

  // ================= scan phase (one block per sample) =================
  unsigned* ep = hist;
  unsigned* en = hist + EG;
  for (int k = t; k < 2 * EG; k += 512) hist[k] = 0u;   // 8192 == NB*4
  if (wid == 0) {   // pooled variance: vart = S_total * (sum 1/c) / NI
    float S = 0.f, rcp = 0.f;
    if (lane >= 1 && lane < NC) {
      float c = sums[132 + lane];
      if (c > 0.f) {
        float sg = sums[66 + lane] / c;
        S = sums[99 + lane] - c * sg * sg;
        rcp = 1.0f / c;
      }
    }
    for (int o = 32; o; o >>= 1) {
      S   += __shfl_down(S, o);
      rcp += __shfl_down(rcp, o);
    }
    if (lane == 0) vart_s = S * rcp / (float)NI;
  }
  __syncthreads();
  // read global t-hist (atomic reads for cross-XCD coherence), scatter to e-grid
  for (int b = t; b < NB; b += 512) {
    ull v = atomicAdd(&th[b], 0ull);
    unsigned pos = (unsigned)(v >> 32), neg = (unsigned)(v & 0xFFFFFFFFu);
    if (pos | neg) {
      float tc = ((float)b + 0.5f) * (1.0f / BSCALE);
      float ex = __expf(-tc);
      if (pos) {
        float e = 2.0f - 2.0f * ex;
        int k = (int)(e * ESCALE); if (k > EG - 1) k = EG - 1;
        atomicAdd(&ep[k], pos);
      }
      if (neg) {
        float e = 2.0f * ex;
        int k = (int)(e * ESCALE); if (k > EG - 1) k = EG - 1;
        atomicAdd(&en[k], neg);
      }
    }
  }
  __syncthreads();
  const int CH = EG / 512;  // 8
  int j0 = t * CH;
  unsigned np = 0, nn = 0;
  for (int k = 0; k < CH; ++k) {
    int b = EG - 1 - (j0 + k);
    np += ep[b]; nn += en[b];
  }
  ull v = ((ull)np << 32) | (ull)nn;
  ull inc = v;
  for (int o = 1; o < 64; o <<= 1) {
    ull u = __shfl_up(inc, o);
    if (lane >= o) inc += u;
  }
  if (lane == 63) wsum[wid] = inc;
  __syncthreads();
  ull offset = 0, total = 0;
  for (int i = 0; i < 8; ++i) {
    ull xr = wsum[i];
    if (i < wid) offset += xr;
    total += xr;
  }
  ull excl = offset + inc - v;
  float P = (float)(unsigned)(total >> 32);
  unsigned p = (unsigned)(excl >> 32), f = (unsigned)(excl & 0xFFFFFFFFu);
  float jprev = 1.0f - (P - (float)p) / (P + (float)f);
  float contrib = 0.f;
  for (int k = 0; k < CH; ++k) {
    int b = EG - 1 - (j0 + k);
    unsigned ap_ = ep[b], an_ = en[b];
    if (ap_ | an_) {
      p += ap_; f += an_;
      float j = 1.0f - (P - (float)p) / (P + (float)f);
      float e = ((float)b + 0.5f) * (2.0f / EG);
      contrib += e * (j - jprev);
      jprev = j;
    }
  }
  for (int o = 32; o; o >>= 1) contrib += __shfl_down(contrib, o);
  if (lane == 0) red[wid] = contrib;
  __syncthreads();
  if (t == 0) {
    float tot = 0.f;
    for (int i = 0; i < 8; ++i) tot += red[i];
    float loss = tot + vart_s;
    float* fin = ws + W_FIN;
    unsigned* cnt = (unsigned*)(fin + 4);
    atomicExch(&fin[s], loss);
    unsigned old = atomicAdd(&cnt[0], 1u);
    if (old == BNUM - 1) {
      float a = 0.f;
      for (int i = 0; i < BNUM; ++i) a += atomicAdd(&fin[i], 0.0f);
      out[0] = a * (1.0f / BNUM);
    }
  }
}

extern "C" void kernel_launch(void* const* d_in, const int* in_sizes, int n_in,
                              void* d_out, int out_size, void* d_ws, size_t ws_size,
                              hipStream_t stream) {
  const float* emb = (const float*)d_in[0];   // [4,2,512,512]
  const float* sig = (const float*)d_in[1];   // [4,1,512,512]
  const int*   gt  = (const int*)d_in[2];     // [4,1,512,512]
  float* out = (float*)d_out;
  float* ws  = (float*)d_ws;

  dim3 gA(64, BNUM);
  stats_kernel<<<gA, 256, 0, stream>>>(emb, sig, gt, ws);
  dim3 gB(128, BNUM);
  hist_scan_kernel<<<gB, 512, 0, stream>>>(emb, gt, ws, out);
}